// Round 15
// baseline (31.106 us; speedup 1.0000x reference)
//
#include <hip/hip_runtime.h>

// Degrade: per-sample depthwise 13x13 cross-correlation, stride 4,
// replicate padding p=6.  im: [8,4,1024,1024] f32, kernel: [8,1,13,13] f32,
// out: [8,4,256,256] f32.
//
// R14 = R12's burst regime (pinned load bursts, progressive vmcnt,
// XCD plane-per-die remap, scatter-partials, compile-time ky-phases)
// with TH 4 -> 8: vertical register reuse 1.56x -> 1.28x amplification,
// beyond-L1 traffic 262 -> 215 MB (theory: residual bind is the L3 port
// serving the vertical re-read).  Rolling window keeps ~20 loads in
// flight per wave while capping live x-regs at 21 (84 VGPR):
//   load ph0(11)+ph1(10) | fma0 | load ph2(10) | fma1 | load ph3(10) | fma2,3
// 5120 waves.  R9's TH=8 failure was the serial-phase regime (latency-
// exposed); this re-tests TH=8 in the burst regime.

#define KS 13
#define IH 1024
#define IW 1024
#define OH 256
#define OW 256
#define WOX 61              // valid outputs per wave in x (3-lane halo)
#define TH 8                // output rows per thread
#define NROWS (4 * TH + 9)  // 41 input rows per thread
#define GRIDX 5
#define GRIDY 8
#define GRIDZ 32
#define NWG (GRIDX * GRIDY * GRIDZ)     // 1280, divisible by 8 XCDs
#define PERX (NWG / 8)                  // 160 blocks per XCD chunk

__device__ __forceinline__ float pick_c(const float4& x, int s) {
    float a = (s & 2) ? x.z : x.x;
    float b = (s & 2) ? x.w : x.y;
    return (s & 1) ? b : a;
}

// ---- issue loads for ky-phase R (rows t = R + 4u, u < N) ----
template <int R, int N, bool EDGE>
__device__ __forceinline__ void load_phase(
    float4 (&x)[N], const float* __restrict__ pl,
    int gy0, int fbase, int cb)
{
#pragma unroll
    for (int u = 0; u < N; ++u) {
        const int t = R + 4 * u;                   // compile-time
        const int gy = min(max(gy0 + t, 0), IH - 1);   // scalar
        x[u] = *(const float4*)(pl + (size_t)gy * IW + (EDGE ? cb : fbase));
    }
}

// ---- consume ky-phase R ----
template <int R, int N, bool EDGE>
__device__ __forceinline__ void fma_phase(
    const float4 (&x)[N], const float* __restrict__ kb, float acc[TH][4],
    bool interior, int s0, int s1, int s2, int s3)
{
#pragma unroll
    for (int u = 0; u < N; ++u) {
        const int t = R + 4 * u;                   // compile-time
        float4 v = x[u];
        if (EDGE && !interior) {                   // border lanes only
            float4 f;
            f.x = pick_c(v, s0); f.y = pick_c(v, s1);
            f.z = pick_c(v, s2); f.w = pick_c(v, s3);
            v = f;
        }
#pragma unroll
        for (int ky = R; ky < KS; ky += 4) {
            const int j = (t - ky) >> 2;           // compile-time
            if (j >= 0 && j < TH) {
                const float* __restrict__ kr = kb + ky * KS;
                // chunk float c -> tap kx=4p+c-2 of output (lane-p)
                acc[j][0] = fmaf(v.z, kr[0],  acc[j][0]);
                acc[j][0] = fmaf(v.w, kr[1],  acc[j][0]);
                acc[j][1] = fmaf(v.x, kr[2],  acc[j][1]);
                acc[j][1] = fmaf(v.y, kr[3],  acc[j][1]);
                acc[j][1] = fmaf(v.z, kr[4],  acc[j][1]);
                acc[j][1] = fmaf(v.w, kr[5],  acc[j][1]);
                acc[j][2] = fmaf(v.x, kr[6],  acc[j][2]);
                acc[j][2] = fmaf(v.y, kr[7],  acc[j][2]);
                acc[j][2] = fmaf(v.z, kr[8],  acc[j][2]);
                acc[j][2] = fmaf(v.w, kr[9],  acc[j][2]);
                acc[j][3] = fmaf(v.x, kr[10], acc[j][3]);
                acc[j][3] = fmaf(v.y, kr[11], acc[j][3]);
                acc[j][3] = fmaf(v.z, kr[12], acc[j][3]);
            }
        }
    }
}

template <bool EDGE>
__device__ __forceinline__ void conv_body(
    const float* __restrict__ pl, const float* __restrict__ kb,
    int gy0, int fbase, int cb, int s0, int s1, int s2, int s3,
    bool interior, float acc[TH][4])
{
    // phase row counts: r=0 -> 11 (t=0..40); r=1,2,3 -> 10
    float4 x0[11], x1[10], x2[10], x3[10];

    load_phase<0, 11, EDGE>(x0, pl, gy0, fbase, cb);
    load_phase<1, 10, EDGE>(x1, pl, gy0, fbase, cb);   // 21 in flight
    __builtin_amdgcn_sched_barrier(0);

    fma_phase<0, 11, EDGE>(x0, kb, acc, interior, s0, s1, s2, s3);
    __builtin_amdgcn_sched_barrier(0);
    load_phase<2, 10, EDGE>(x2, pl, gy0, fbase, cb);   // refill
    __builtin_amdgcn_sched_barrier(0);

    fma_phase<1, 10, EDGE>(x1, kb, acc, interior, s0, s1, s2, s3);
    __builtin_amdgcn_sched_barrier(0);
    load_phase<3, 10, EDGE>(x3, pl, gy0, fbase, cb);   // refill
    __builtin_amdgcn_sched_barrier(0);

    fma_phase<2, 10, EDGE>(x2, kb, acc, interior, s0, s1, s2, s3);
    fma_phase<3, 10, EDGE>(x3, kb, acc, interior, s0, s1, s2, s3);
}

__global__ __launch_bounds__(256) void degrade_kernel(
    const float* __restrict__ im,
    const float* __restrict__ kern,
    float* __restrict__ out)
{
    // ---- XCD-aware decode: y-adjacent blocks + whole planes per XCD ----
    const int h   = blockIdx.x;                    // round-robins XCDs
    const int lid = (h & 7) * PERX + (h >> 3);     // bijective remap
    const int by  = lid & 7;                       // y fastest (8 y-blocks)
    const int tXZ = lid >> 3;
    const int bx  = tXZ % GRIDX;
    const int bz  = tXZ / GRIDX;                   // 4 planes per XCD

    const int plane = bz;                  // b*4 + c
    const int b     = plane >> 2;
    const int tid   = threadIdx.x;
    const int lane  = tid & 63;
    const int w     = __builtin_amdgcn_readfirstlane(tid >> 6);
    const int ox0   = bx * WOX;
    const int oy0   = by * (4 * TH) + w * TH;      // scalar

    const float* __restrict__ pl = im + (size_t)plane * (IH * IW);
    const float* __restrict__ kb = kern + b * (KS * KS);   // wave-uniform

    // this lane's 16B chunk: floats fbase..fbase+3 of each input row
    const int fbase = 4 * ox0 - 8 + 4 * lane;
    const int cb    = min(max(fbase, 0), IW - 4);
    const bool interior = (fbase == cb);
    const int s0 = min(max(fbase + 0, 0), IW - 1) - cb;
    const int s1 = min(max(fbase + 1, 0), IW - 1) - cb;
    const int s2 = min(max(fbase + 2, 0), IW - 1) - cb;
    const int s3 = min(max(fbase + 3, 0), IW - 1) - cb;

    const int gy0 = 4 * oy0 - 6;           // scalar

    float acc[TH][4];
#pragma unroll
    for (int j = 0; j < TH; ++j)
#pragma unroll
        for (int p = 0; p < 4; ++p) acc[j][p] = 0.0f;

    // blocks bx=1..3 are provably interior (fbase in [236,979])
    if (bx == 0 || bx == GRIDX - 1)
        conv_body<true >(pl, kb, gy0, fbase, cb, s0, s1, s2, s3, interior, acc);
    else
        conv_body<false>(pl, kb, gy0, fbase, cb, s0, s1, s2, s3, interior, acc);

    // combine partials across lanes (once) and store
    const bool valid = (lane < WOX) && (ox0 + lane < OW);
#pragma unroll
    for (int j = 0; j < TH; ++j) {
        float v = acc[j][0]
                + __shfl(acc[j][1], lane + 1, 64)
                + __shfl(acc[j][2], lane + 2, 64)
                + __shfl(acc[j][3], lane + 3, 64);
        if (valid)
            out[((size_t)plane * OH + oy0 + j) * OW + ox0 + lane] = v;
    }
}

extern "C" void kernel_launch(void* const* d_in, const int* in_sizes, int n_in,
                              void* d_out, int out_size, void* d_ws, size_t ws_size,
                              hipStream_t stream)
{
    const float* im   = (const float*)d_in[0];
    const float* kern = (const float*)d_in[1];
    float* out        = (float*)d_out;

    degrade_kernel<<<dim3(NWG, 1, 1), 256, 0, stream>>>(im, kern, out);
}

// Round 16
// 29.670 us; speedup vs baseline: 1.0484x; 1.0484x over previous
//
#include <hip/hip_runtime.h>

// Degrade: per-sample depthwise 13x13 cross-correlation, stride 4,
// replicate padding p=6.  im: [8,4,1024,1024] f32, kernel: [8,1,13,13] f32,
// out: [8,4,256,256] f32.
//
// R15 = R12 verbatim (the measured optimum, 29.7us).  Lever post-mortems:
//   R11 locality (XCD plane-per-die + y-contiguous walk): -10%
//   R12 full-depth pinned load burst (25 outstanding/wave): -18%
//   R13 +occupancy at depth 19: null  (per-CU outstanding already saturated)
//   R14 -18% traffic via TH=8 (FETCH 87->66 MB): SLOWER (31.1) -> not
//       beyond-L2-traffic-bound; wave count loss dominates.
// Conclusion: latency-x-concurrency wall of the gather stream at
// ~8.8 TB/s effective beyond-L1; 1.37x over the un-achievable pure-copy
// floor.  Declaring this the practical roofline for the structure.

#define KS 13
#define IH 1024
#define IW 1024
#define OH 256
#define OW 256
#define WOX 61              // valid outputs per wave in x (3-lane halo)
#define TH 4                // output rows per thread
#define NROWS (4 * TH + 9)  // 25 input rows per thread
#define GRIDX 5
#define GRIDY 16
#define GRIDZ 32
#define NWG (GRIDX * GRIDY * GRIDZ)     // 2560, divisible by 8 XCDs
#define PERX (NWG / 8)                  // 320 blocks per XCD chunk

__device__ __forceinline__ float pick_c(const float4& x, int s) {
    float a = (s & 2) ? x.z : x.x;
    float b = (s & 2) ? x.w : x.y;
    return (s & 1) ? b : a;
}

template <bool EDGE>
__device__ __forceinline__ void conv_body(
    const float* __restrict__ pl, const float* __restrict__ kb,
    int gy0, int fbase, int cb, int s0, int s1, int s2, int s3,
    bool interior, float acc[TH][4])
{
    float4 x[NROWS];          // 100 VGPR; all indices compile-time

    // ---- issue ALL row loads, phase-major (t = r + 4u) ----
    {
        int c = 0;            // folds to constants under full unroll
#pragma unroll
        for (int r = 0; r < 4; ++r) {
#pragma unroll
            for (int u = 0; u < 7; ++u) {
                const int t = r + 4 * u;
                if (t < NROWS) {
                    const int gy = min(max(gy0 + t, 0), IH - 1);  // scalar
                    const float* __restrict__ row = pl + (size_t)gy * IW;
                    x[c] = *(const float4*)(row + (EDGE ? cb : fbase));
                    ++c;
                }
            }
        }
    }
    // pin the load burst above the FMA section (compiler would otherwise
    // sink loads to just-before-use, collapsing MLP back to ~7)
    __builtin_amdgcn_sched_barrier(0);

    // ---- consume in issue order: progressive vmcnt waits ----
    {
        int c = 0;
#pragma unroll
        for (int r = 0; r < 4; ++r) {
#pragma unroll
            for (int u = 0; u < 7; ++u) {
                const int t = r + 4 * u;
                if (t < NROWS) {
                    float4 v = x[c]; ++c;
                    if (EDGE) {
                        if (!interior) {          // border lanes only
                            float4 f;
                            f.x = pick_c(v, s0); f.y = pick_c(v, s1);
                            f.z = pick_c(v, s2); f.w = pick_c(v, s3);
                            v = f;
                        }
                    }
#pragma unroll
                    for (int ky = r; ky < KS; ky += 4) {
                        const int j = (t - ky) >> 2;   // compile-time
                        if (j >= 0 && j < TH) {
                            const float* __restrict__ kr = kb + ky * KS;
                            // chunk float c -> tap kx=4p+c-2 of out (lane-p)
                            acc[j][0] = fmaf(v.z, kr[0],  acc[j][0]);
                            acc[j][0] = fmaf(v.w, kr[1],  acc[j][0]);
                            acc[j][1] = fmaf(v.x, kr[2],  acc[j][1]);
                            acc[j][1] = fmaf(v.y, kr[3],  acc[j][1]);
                            acc[j][1] = fmaf(v.z, kr[4],  acc[j][1]);
                            acc[j][1] = fmaf(v.w, kr[5],  acc[j][1]);
                            acc[j][2] = fmaf(v.x, kr[6],  acc[j][2]);
                            acc[j][2] = fmaf(v.y, kr[7],  acc[j][2]);
                            acc[j][2] = fmaf(v.z, kr[8],  acc[j][2]);
                            acc[j][2] = fmaf(v.w, kr[9],  acc[j][2]);
                            acc[j][3] = fmaf(v.x, kr[10], acc[j][3]);
                            acc[j][3] = fmaf(v.y, kr[11], acc[j][3]);
                            acc[j][3] = fmaf(v.z, kr[12], acc[j][3]);
                        }
                    }
                }
            }
        }
    }
}

__global__ __launch_bounds__(256) void degrade_kernel(
    const float* __restrict__ im,
    const float* __restrict__ kern,
    float* __restrict__ out)
{
    // ---- XCD-aware decode: y-adjacent blocks + whole planes per XCD ----
    const int h   = blockIdx.x;                    // round-robins XCDs
    const int lid = (h & 7) * PERX + (h >> 3);     // bijective remap
    const int by  = lid & 15;                      // y fastest
    const int tXZ = lid >> 4;
    const int bx  = tXZ % GRIDX;
    const int bz  = tXZ / GRIDX;

    const int plane = bz;                  // b*4 + c
    const int b     = plane >> 2;
    const int tid   = threadIdx.x;
    const int lane  = tid & 63;
    const int w     = __builtin_amdgcn_readfirstlane(tid >> 6);
    const int ox0   = bx * WOX;
    const int oy0   = by * (4 * TH) + w * TH;      // scalar

    const float* __restrict__ pl = im + (size_t)plane * (IH * IW);
    const float* __restrict__ kb = kern + b * (KS * KS);   // wave-uniform

    // this lane's 16B chunk: floats fbase..fbase+3 of each input row
    const int fbase = 4 * ox0 - 8 + 4 * lane;
    const int cb    = min(max(fbase, 0), IW - 4);
    const bool interior = (fbase == cb);
    const int s0 = min(max(fbase + 0, 0), IW - 1) - cb;
    const int s1 = min(max(fbase + 1, 0), IW - 1) - cb;
    const int s2 = min(max(fbase + 2, 0), IW - 1) - cb;
    const int s3 = min(max(fbase + 3, 0), IW - 1) - cb;

    const int gy0 = 4 * oy0 - 6;           // scalar

    float acc[TH][4];
#pragma unroll
    for (int j = 0; j < TH; ++j)
#pragma unroll
        for (int p = 0; p < 4; ++p) acc[j][p] = 0.0f;

    // blocks bx=1..3 are provably interior (fbase in [236,979])
    if (bx == 0 || bx == GRIDX - 1)
        conv_body<true >(pl, kb, gy0, fbase, cb, s0, s1, s2, s3, interior, acc);
    else
        conv_body<false>(pl, kb, gy0, fbase, cb, s0, s1, s2, s3, interior, acc);

    // combine partials across lanes (once) and store
    const bool valid = (lane < WOX) && (ox0 + lane < OW);
#pragma unroll
    for (int j = 0; j < TH; ++j) {
        float v = acc[j][0]
                + __shfl(acc[j][1], lane + 1, 64)
                + __shfl(acc[j][2], lane + 2, 64)
                + __shfl(acc[j][3], lane + 3, 64);
        if (valid)
            out[((size_t)plane * OH + oy0 + j) * OW + ox0 + lane] = v;
    }
}

extern "C" void kernel_launch(void* const* d_in, const int* in_sizes, int n_in,
                              void* d_out, int out_size, void* d_ws, size_t ws_size,
                              hipStream_t stream)
{
    const float* im   = (const float*)d_in[0];
    const float* kern = (const float*)d_in[1];
    float* out        = (float*)d_out;

    degrade_kernel<<<dim3(NWG, 1, 1), 256, 0, stream>>>(im, kern, out);
}